// Round 16
// baseline (673.945 us; speedup 1.0000x reference)
//
#include <hip/hip_runtime.h>
#include <hip/hip_bf16.h>

typedef short short8 __attribute__((ext_vector_type(8)));
typedef float f32x4 __attribute__((ext_vector_type(4)));

#define AS1(p) ((const __attribute__((address_space(1))) void*)(p))
#define AS3(p) ((__attribute__((address_space(3))) void*)(p))

__device__ __forceinline__ ushort f2bf(float f) {
  __hip_bfloat16 h = __float2bfloat16(f);
  return *reinterpret_cast<const ushort*>(&h);
}
__device__ __forceinline__ float bfu2f(ushort u) {
  unsigned int x = ((unsigned int)u) << 16;
  float f;
  __builtin_memcpy(&f, &x, 4);
  return f;
}
__device__ __forceinline__ float silu_f(float v) { return v / (1.f + __expf(-v)); }

// ---------------- LayerNorm fp32-in -> bf16 out (stem only, D = 1024) -------
template<int NV>
__global__ __launch_bounds__(256) void ln_bf16_k(
    const float* __restrict__ in, const float* __restrict__ sc,
    const float* __restrict__ bi, ushort* __restrict__ out)
{
  const int D = NV * 1024;
  const long row = blockIdx.x;
  const int tx = threadIdx.x;
  const float* p = in + row * (long)D;
  float4 v[NV];
  float s = 0.f, s2 = 0.f;
#pragma unroll
  for (int t = 0; t < NV; ++t) {
    v[t] = *reinterpret_cast<const float4*>(p + t * 1024 + tx * 4);
    s  += v[t].x + v[t].y + v[t].z + v[t].w;
    s2 += v[t].x * v[t].x + v[t].y * v[t].y + v[t].z * v[t].z + v[t].w * v[t].w;
  }
#pragma unroll
  for (int o = 1; o < 64; o <<= 1) { s += __shfl_xor(s, o); s2 += __shfl_xor(s2, o); }
  __shared__ float red[2][4];
  const int wave = tx >> 6;
  if ((tx & 63) == 0) { red[0][wave] = s; red[1][wave] = s2; }
  __syncthreads();
  s  = red[0][0] + red[0][1] + red[0][2] + red[0][3];
  s2 = red[1][0] + red[1][1] + red[1][2] + red[1][3];
  const float mu   = s / D;
  const float rstd = rsqrtf(s2 / D - mu * mu + 1e-6f);
#pragma unroll
  for (int t = 0; t < NV; ++t) {
    const int d = t * 1024 + tx * 4;
    float4 g = *reinterpret_cast<const float4*>(sc + d);
    float4 b = *reinterpret_cast<const float4*>(bi + d);
    ushort4 o;
    o.x = f2bf((v[t].x - mu) * rstd * g.x + b.x);
    o.y = f2bf((v[t].y - mu) * rstd * g.y + b.y);
    o.z = f2bf((v[t].z - mu) * rstd * g.z + b.z);
    o.w = f2bf((v[t].w - mu) * rstd * g.w + b.w);
    *reinterpret_cast<ushort4*>(out + row * (long)D + d) = o;
  }
}

// ---------------- row stats: bf16 h (D=2048) -> {mu*rstd, rstd} -------------
__global__ __launch_bounds__(256) void ln_stats_k(
    const ushort* __restrict__ in, float2* __restrict__ stats)
{
  const long row = blockIdx.x;
  const int tx = threadIdx.x;
  short8 v8 = *reinterpret_cast<const short8*>(in + row * 2048 + tx * 8);
  float s = 0.f, s2 = 0.f;
#pragma unroll
  for (int j = 0; j < 8; ++j) {
    const float v = bfu2f((ushort)v8[j]);
    s += v; s2 += v * v;
  }
#pragma unroll
  for (int o = 1; o < 64; o <<= 1) { s += __shfl_xor(s, o); s2 += __shfl_xor(s2, o); }
  __shared__ float red[2][4];
  const int wave = tx >> 6;
  if ((tx & 63) == 0) { red[0][wave] = s; red[1][wave] = s2; }
  __syncthreads();
  if (tx == 0) {
    s  = red[0][0] + red[0][1] + red[0][2] + red[0][3];
    s2 = red[1][0] + red[1][1] + red[1][2] + red[1][3];
    const float mu   = s * (1.f / 2048.f);
    const float rstd = rsqrtf(s2 * (1.f / 2048.f) - mu * mu + 1e-6f);
    stats[row] = make_float2(mu * rstd, rstd);
  }
}

// ---------------- fp32 [K][N] -> bf16 [N][K] (plain, for w1; r11 verified) --
__global__ __launch_bounds__(256) void transpose_bf16_k(
    const float* __restrict__ in, ushort* __restrict__ out, int K, int N)
{
  __shared__ float tile[64][65];
  const int k0 = blockIdx.y * 64, n0 = blockIdx.x * 64;
  const int tx = threadIdx.x, ty = threadIdx.y;
#pragma unroll
  for (int r = ty; r < 64; r += 4)
    tile[r][tx] = in[(long)(k0 + r) * N + n0 + tx];
  __syncthreads();
#pragma unroll
  for (int r = ty; r < 64; r += 4)
    out[(long)(n0 + r) * K + k0 + tx] = f2bf(tile[tx][r]);
}

// -- batched (z): fp32 [K][N] -> bf16 [N][K] scaled by g[k]; NO atomics ------
// load/LDS side identical to r14-verified version; store side ushort2
// (2 cols/thread, 256B per wave-store-instr; LDS reads 2-way alias = free).
__global__ void transpose_scale_k(
    const float* __restrict__ in0, const float* __restrict__ g0,
    const float* __restrict__ beta0, ushort* __restrict__ out0,
    float2* __restrict__ pup, int K, int N)
{
  __shared__ float tile[64][65];
  __shared__ float2 pred[4][64];
  const int z = blockIdx.z;
  const float* in    = in0 + (long)z * K * N;
  const float* g     = g0 + (long)z * K;
  const float* beta  = beta0 + (long)z * K;
  ushort* out        = out0 + (long)z * K * N;
  const int k0 = blockIdx.y * 64, n0 = blockIdx.x * 64;
  const int t  = threadIdx.x + threadIdx.y * 64;
  const int tx = t & 63, ty = t >> 6;
  float pu = 0.f, pv = 0.f;
#pragma unroll
  for (int r = ty; r < 64; r += 4) {
    const float w  = in[(long)(k0 + r) * N + n0 + tx];
    const float ws = g[k0 + r] * w;
    tile[r][tx] = ws;
    pu += ws;
    pv += beta[k0 + r] * w;
  }
  pred[ty][tx] = make_float2(pu, pv);
  __syncthreads();
  if (ty == 0) {
    const float2 a = pred[0][tx], b = pred[1][tx], c = pred[2][tx], d = pred[3][tx];
    const long ZN = (long)gridDim.z * N;
    pup[(long)blockIdx.y * ZN + (long)z * N + n0 + tx] =
        make_float2(a.x + b.x + c.x + d.x, a.y + b.y + c.y + d.y);
  }
  // ushort2 stores: thread -> (row nr, col pair c2); 8 iters cover 64x64
  const int c2 = (t & 31) * 2;
  const int tg = t >> 5;  // 0..7
#pragma unroll
  for (int it = 0; it < 8; ++it) {
    const int nr = tg + it * 8;
    ushort2 o;
    o.x = f2bf(tile[c2][nr]);
    o.y = f2bf(tile[c2 + 1][nr]);
    *reinterpret_cast<ushort2*>(out + (long)(n0 + nr) * K + k0 + c2) = o;
  }
}

// ---------------- reduce pup[NK][ZN] -> uvw[ZN] ------------------------------
__global__ __launch_bounds__(256) void uv_reduce_k(
    const float2* __restrict__ pup, float2* __restrict__ uvw, int NK, int ZN)
{
  const int c = blockIdx.x * 256 + threadIdx.x;
  float sx = 0.f, sy = 0.f;
  for (int k = 0; k < NK; ++k) {
    const float2 v = pup[(long)k * ZN + c];
    sx += v.x; sy += v.y;
  }
  uvw[c] = make_float2(sx, sy);
}

// ============================================================================
// 256x256 GEMM — r9/r11 pipelined core, 16x16x32 MFMA (verified best:
// 72.6us / 947 TF / 0 bank conflicts). Modes:
//   MODE 0: C = silu(acc+bias) -> bf16                       (stem)
//   MODE 3: C = Rin + silu(rstd*acc - mu*rstd*u + v + b) -> bf16 (block)
//   MODE 5: split-K=2 head: kb=bid>>7; both halves unsafeAtomicAdd into
//           pre-zeroed f32 out (2 commutative adds/elem -> deterministic).
// ============================================================================
#define STG(gsrc, ldst)                                                          \
  __builtin_amdgcn_global_load_lds(AS1(gsrc),          AS3(ldst),          16, 0, 0); \
  __builtin_amdgcn_global_load_lds(AS1((gsrc) + offQ), AS3((ldst) + 8192), 16, 0, 0)

#define ldsA(B, H) (ldsW + (B) * 65536 + (H) * 16384)
#define ldsB(B, H) (ldsW + (B) * 65536 + 32768 + (H) * 16384)

#define RD_AF(DST, DB, MH, KS)                                                  \
  _Pragma("unroll") for (int i_ = 0; i_ < 4; ++i_)                              \
    DST[i_] = *(const short8*)(smem + (DB) * 65536 + aOff + ((MH) * 4 + i_) * 2048 + rdk[(KS)])

#define RD_BF(DST, DB, KS)                                                      \
  _Pragma("unroll") for (int j_ = 0; j_ < 4; ++j_)                              \
    DST[j_] = *(const short8*)(smem + (DB) * 65536 + bOff + j_ * 2048 + rdk[(KS)])

#define MFMA16(AREG, MH, BREG)                                                  \
  _Pragma("unroll") for (int i_ = 0; i_ < 4; ++i_)                              \
  _Pragma("unroll") for (int j_ = 0; j_ < 4; ++j_)                              \
    acc[(MH) * 4 + i_][j_] = __builtin_amdgcn_mfma_f32_16x16x32_bf16(           \
        AREG[i_], BREG[j_], acc[(MH) * 4 + i_][j_], 0, 0, 0)

#define BARRIER __builtin_amdgcn_s_barrier()
#define SP1 __builtin_amdgcn_s_setprio(1)
#define SP0 __builtin_amdgcn_s_setprio(0)
#define SBAR __builtin_amdgcn_sched_barrier(0)
#define LGKMW(N) do { asm volatile("s_waitcnt lgkmcnt(" #N ")"); SBAR; } while (0)
#define W4 do { asm volatile("s_waitcnt vmcnt(4)" ::: "memory"); SBAR; } while (0)
#define W0 do { asm volatile("s_waitcnt vmcnt(0)" ::: "memory"); SBAR; } while (0)
#define WN do {} while (0)

#define DO_TILE(DB, S1, AO, S2, BO, WAITE)                                      \
  RD_AF(afx, DB, 0, 0);                                                         \
  RD_BF(bf, DB, 0);                                                             \
  RD_AF(afy, DB, 1, 0);                                                         \
  if (S1) { STG(aP + (AO), ldsA((DB) ^ 1, 0));                                  \
            STG(aP + (AO) + offH, ldsA((DB) ^ 1, 1)); }                         \
  LGKMW(4);                                                                     \
  SP1; MFMA16(afx, 0, bf); SP0;                                                 \
  RD_AF(afx, DB, 0, 1);                                                         \
  LGKMW(4);                                                                     \
  SP1; MFMA16(afy, 1, bf); SP0;                                                 \
  RD_BF(bf, DB, 1);                                                             \
  SBAR;                                                                         \
  RD_AF(afy, DB, 1, 1);                                                         \
  LGKMW(4);                                                                     \
  SP1; MFMA16(afx, 0, bf); SP0;                                                 \
  BARRIER;                                                                      \
  if (S2) { STG(bP + (BO), ldsB(DB, 0));                                        \
            STG(bP + (BO) + offH, ldsB(DB, 1)); }                               \
  LGKMW(0);                                                                     \
  SP1; MFMA16(afy, 1, bf); SP0;                                                 \
  WAITE;                                                                        \
  BARRIER;

template<int MODE>
__global__ __launch_bounds__(512, 2) void gemm256_k(
    const ushort* __restrict__ A, const ushort* __restrict__ Bt,
    const float* __restrict__ bias, const float2* __restrict__ stats,
    const float2* __restrict__ uvw, const ushort* __restrict__ Rin,
    void* __restrict__ Cv, float* __restrict__ Cv2,
    int M, int N, int K, int ld)
{
  extern __shared__ char smem[];
  const int tid = threadIdx.x;
  const int lane = tid & 63, wid = tid >> 6;
  const int wr = wid >> 2, wc = wid & 3;
  const int nbx = N >> 8;

  int bid;
  {
    const int b = blockIdx.x;
    const int cpx = gridDim.x >> 3;
    bid = (b & 7) * cpx + (b >> 3);
  }
  int kb = 0;
  if (MODE == 5) { kb = bid >> 7; bid &= 127; }
  const int bx = bid % nbx, by = bid / nbx;
  const long m0 = (long)by << 8, n0 = (long)bx << 8;

  const int srow = tid >> 3;
  const int scol = (((tid & 7) * 16) ^ (((tid >> 3) & 7) << 4)) >> 1;
  const ushort* aP = A  + (long)kb * 1024 + (m0 + srow) * (long)ld + scol;
  const ushort* bP = Bt + (long)kb * 1024 + (n0 + srow) * (long)ld + scol;
  const long offH = 128L * ld, offQ = 64L * ld;
  char* ldsW = smem + wid * 1024;

  int rdk[2];
  rdk[0] = (((lane >> 4) * 16)     ) ^ ((lane & 7) << 4);
  rdk[1] = (((lane >> 4) * 16) + 64) ^ ((lane & 7) << 4);
  const int aOff = wr * 16384 + (lane & 15) * 128;
  const int bOff = 32768 + (wc >> 1) * 16384 + ((wc & 1) * 64 + (lane & 15)) * 128;

  f32x4 acc[8][4] = {};
  const int NT = K >> 6;  // even, >= 4

  // prologue: A(0), B(0), B(1); keep B(1) in flight
  STG(aP,      ldsA(0, 0));  STG(aP + offH,      ldsA(0, 1));
  STG(bP,      ldsB(0, 0));  STG(bP + offH,      ldsB(0, 1));
  STG(bP + 64, ldsB(1, 0));  STG(bP + 64 + offH, ldsB(1, 1));
  W4;
  BARRIER;

  short8 afx[4], afy[4], bf[4];
  for (int t = 0; t < NT - 2; t += 2) {
    DO_TILE(0, 1,  64, 1, 128, W4)
    DO_TILE(1, 1, 128, 1, 192, W4)
    aP += 128; bP += 128;
  }
  DO_TILE(0, 1, 64, 0, 0, W0)
  DO_TILE(1, 0,  0, 0, 0, WN)

  // ---- epilogue: C/D layout col=lane&15, row=(lane>>4)*4+reg ----
  if (MODE == 0) {
#pragma unroll
    for (int j = 0; j < 4; ++j) {
      const long col = n0 + wc * 64 + j * 16 + (lane & 15);
      const float bj = bias[col];
#pragma unroll
      for (int i = 0; i < 8; ++i) {
        const long rowb = m0 + wr * 128 + i * 16 + ((lane >> 4) << 2);
#pragma unroll
        for (int r = 0; r < 4; ++r) {
          const float v = acc[i][j][r] + bj;
          ((ushort*)Cv)[(rowb + r) * N + col] = f2bf(silu_f(v));
        }
      }
    }
  } else {
    float2 uvv[4];
    float  bj4[4];
    long   col4[4];
#pragma unroll
    for (int j = 0; j < 4; ++j) {
      col4[j] = n0 + wc * 64 + j * 16 + (lane & 15);
      uvv[j]  = uvw[col4[j]];
      bj4[j]  = bias[col4[j]];
    }
    const float cw = (MODE == 5 && kb == 1) ? 0.f : 1.f;
#pragma unroll
    for (int i = 0; i < 8; ++i) {
      const long rowb = m0 + wr * 128 + i * 16 + ((lane >> 4) << 2);
#pragma unroll
      for (int r = 0; r < 4; ++r) {
        const long row = rowb + r;
        const float2 ms = stats[row];  // {mu*rstd, rstd}
#pragma unroll
        for (int j = 0; j < 4; ++j) {
          const long idx = row * (long)N + col4[j];
          if (MODE == 3) {
            const float v = ms.y * acc[i][j][r] - ms.x * uvv[j].x + uvv[j].y + bj4[j];
            ((ushort*)Cv)[idx] = f2bf(bfu2f(Rin[idx]) + silu_f(v));
          } else {
            const float v = ms.y * acc[i][j][r]
                          + cw * (uvv[j].y + bj4[j] - ms.x * uvv[j].x);
            unsafeAtomicAdd(&((float*)Cv)[idx], v);
          }
        }
      }
    }
  }
}

// ---------------------------------------------------------------------------
extern "C" void kernel_launch(void* const* d_in, const int* in_sizes, int n_in,
                              void* d_out, int out_size, void* d_ws, size_t ws_size,
                              hipStream_t stream) {
  const float* x     = (const float*)d_in[0];
  const float* ln1_s = (const float*)d_in[1];
  const float* ln1_b = (const float*)d_in[2];
  const float* w1    = (const float*)d_in[3];
  const float* b1    = (const float*)d_in[4];
  const float* bln_s = (const float*)d_in[5];
  const float* bln_b = (const float*)d_in[6];
  const float* bws   = (const float*)d_in[7];
  const float* bbs   = (const float*)d_in[8];
  const float* ln2_s = (const float*)d_in[9];
  const float* ln2_b = (const float*)d_in[10];
  const float* w2    = (const float*)d_in[11];
  const float* b2    = (const float*)d_in[12];
  float* out = (float*)d_out;

  const int M = 8192;
  char* ws = (char*)d_ws;
  ushort* h0    = (ushort*)ws;                          // 8192x2048 bf16 = 32MB
  ushort* h1    = (ushort*)(ws + 33554432);             // 32MB (stem Abf)
  ushort* Abf   = h1;
  ushort* wt    = (ushort*)(ws + 67108864);             // bf16 weights^T, 56MB
  float2* uvw   = (float2*)(ws + 125829120);            // 7 x 2048 float2
  float2* stats = (float2*)(ws + 125829120 + 131072);   // 8192 float2
  float2* pupA  = (float2*)(ws + 125829120 + 131072 + 65536);          // 32x12288 f2
  float2* pupB  = (float2*)(ws + 125829120 + 131072 + 65536 + 3145728); // 32x1024 f2
  const long W1T = 0;
  const long BLK = 2097152;
  const long W2T = BLK + 6L * 4194304;

  (void)hipFuncSetAttribute((const void*)gemm256_k<0>,
      hipFuncAttributeMaxDynamicSharedMemorySize, 131072);
  (void)hipFuncSetAttribute((const void*)gemm256_k<3>,
      hipFuncAttributeMaxDynamicSharedMemorySize, 131072);
  (void)hipFuncSetAttribute((const void*)gemm256_k<5>,
      hipFuncAttributeMaxDynamicSharedMemorySize, 131072);

  dim3 tb(64, 4);
  transpose_bf16_k<<<dim3(32, 16), tb, 0, stream>>>(w1, wt + W1T, 1024, 2048);
  transpose_scale_k<<<dim3(32, 32, 6), tb, 0, stream>>>(
      bws, bln_s, bln_b, wt + BLK, pupA, 2048, 2048);
  uv_reduce_k<<<48, 256, 0, stream>>>(pupA, uvw, 32, 12288);
  transpose_scale_k<<<dim3(16, 32, 1), tb, 0, stream>>>(
      w2, ln2_s, ln2_b, wt + W2T, pupB, 2048, 1024);
  uv_reduce_k<<<4, 256, 0, stream>>>(pupB, uvw + 6L * 2048, 32, 1024);

  // zero head output (atomic split-K accumulates into it)
  (void)hipMemsetAsync(out, 0, (size_t)M * 1024 * sizeof(float), stream);

  // stem: h0 = silu(LN(x) @ w1 + b1)
  ln_bf16_k<1><<<M, 256, 0, stream>>>(x, ln1_s, ln1_b, Abf);
  gemm256_k<0><<<32 * 8, 512, 131072, stream>>>(
      Abf, wt + W1T, b1, nullptr, nullptr, nullptr,
      (void*)h0, nullptr, M, 2048, 1024, 1024);

  // residual blocks (folded LN): h_out = h_in + silu(affine(h_in @ W'))
  ushort* hin = h0;
  ushort* hout = h1;
  for (int i = 0; i < 6; ++i) {
    ln_stats_k<<<M, 256, 0, stream>>>(hin, stats);
    gemm256_k<3><<<32 * 8, 512, 131072, stream>>>(
        hin, wt + BLK + (long)i * 4194304, bbs + i * 2048, stats,
        uvw + (long)i * 2048, hin, (void*)hout, nullptr, M, 2048, 2048, 2048);
    ushort* tmp = hin; hin = hout; hout = tmp;
  }

  // head (folded LN, split-K=2, deterministic atomic accumulate)
  ln_stats_k<<<M, 256, 0, stream>>>(hin, stats);
  gemm256_k<5><<<32 * 4 * 2, 512, 131072, stream>>>(
      hin, wt + W2T, b2, stats, uvw + 6L * 2048, nullptr,
      (void*)out, nullptr, M, 1024, 1024, 2048);
}

// Round 17
// 643.886 us; speedup vs baseline: 1.0467x; 1.0467x over previous
//
#include <hip/hip_runtime.h>
#include <hip/hip_bf16.h>

typedef short short8 __attribute__((ext_vector_type(8)));
typedef float f32x4 __attribute__((ext_vector_type(4)));

#define AS1(p) ((const __attribute__((address_space(1))) void*)(p))
#define AS3(p) ((__attribute__((address_space(3))) void*)(p))

__device__ __forceinline__ ushort f2bf(float f) {
  __hip_bfloat16 h = __float2bfloat16(f);
  return *reinterpret_cast<const ushort*>(&h);
}
__device__ __forceinline__ float bfu2f(ushort u) {
  unsigned int x = ((unsigned int)u) << 16;
  float f;
  __builtin_memcpy(&f, &x, 4);
  return f;
}
__device__ __forceinline__ float silu_f(float v) { return v / (1.f + __expf(-v)); }

// ---------------- LayerNorm fp32-in -> bf16 out (stem only, D = 1024) -------
template<int NV>
__global__ __launch_bounds__(256) void ln_bf16_k(
    const float* __restrict__ in, const float* __restrict__ sc,
    const float* __restrict__ bi, ushort* __restrict__ out)
{
  const int D = NV * 1024;
  const long row = blockIdx.x;
  const int tx = threadIdx.x;
  const float* p = in + row * (long)D;
  float4 v[NV];
  float s = 0.f, s2 = 0.f;
#pragma unroll
  for (int t = 0; t < NV; ++t) {
    v[t] = *reinterpret_cast<const float4*>(p + t * 1024 + tx * 4);
    s  += v[t].x + v[t].y + v[t].z + v[t].w;
    s2 += v[t].x * v[t].x + v[t].y * v[t].y + v[t].z * v[t].z + v[t].w * v[t].w;
  }
#pragma unroll
  for (int o = 1; o < 64; o <<= 1) { s += __shfl_xor(s, o); s2 += __shfl_xor(s2, o); }
  __shared__ float red[2][4];
  const int wave = tx >> 6;
  if ((tx & 63) == 0) { red[0][wave] = s; red[1][wave] = s2; }
  __syncthreads();
  s  = red[0][0] + red[0][1] + red[0][2] + red[0][3];
  s2 = red[1][0] + red[1][1] + red[1][2] + red[1][3];
  const float mu   = s / D;
  const float rstd = rsqrtf(s2 / D - mu * mu + 1e-6f);
#pragma unroll
  for (int t = 0; t < NV; ++t) {
    const int d = t * 1024 + tx * 4;
    float4 g = *reinterpret_cast<const float4*>(sc + d);
    float4 b = *reinterpret_cast<const float4*>(bi + d);
    ushort4 o;
    o.x = f2bf((v[t].x - mu) * rstd * g.x + b.x);
    o.y = f2bf((v[t].y - mu) * rstd * g.y + b.y);
    o.z = f2bf((v[t].z - mu) * rstd * g.z + b.z);
    o.w = f2bf((v[t].w - mu) * rstd * g.w + b.w);
    *reinterpret_cast<ushort4*>(out + row * (long)D + d) = o;
  }
}

// ---------------- row stats: bf16 h (D=2048) -> {mu*rstd, rstd} -------------
__global__ __launch_bounds__(256) void ln_stats_k(
    const ushort* __restrict__ in, float2* __restrict__ stats)
{
  const long row = blockIdx.x;
  const int tx = threadIdx.x;
  short8 v8 = *reinterpret_cast<const short8*>(in + row * 2048 + tx * 8);
  float s = 0.f, s2 = 0.f;
#pragma unroll
  for (int j = 0; j < 8; ++j) {
    const float v = bfu2f((ushort)v8[j]);
    s += v; s2 += v * v;
  }
#pragma unroll
  for (int o = 1; o < 64; o <<= 1) { s += __shfl_xor(s, o); s2 += __shfl_xor(s2, o); }
  __shared__ float red[2][4];
  const int wave = tx >> 6;
  if ((tx & 63) == 0) { red[0][wave] = s; red[1][wave] = s2; }
  __syncthreads();
  if (tx == 0) {
    s  = red[0][0] + red[0][1] + red[0][2] + red[0][3];
    s2 = red[1][0] + red[1][1] + red[1][2] + red[1][3];
    const float mu   = s * (1.f / 2048.f);
    const float rstd = rsqrtf(s2 * (1.f / 2048.f) - mu * mu + 1e-6f);
    stats[row] = make_float2(mu * rstd, rstd);
  }
}

// ---------------- fp32 [K][N] -> bf16 [N][K] (plain, for w1; r11 verified) --
__global__ __launch_bounds__(256) void transpose_bf16_k(
    const float* __restrict__ in, ushort* __restrict__ out, int K, int N)
{
  __shared__ float tile[64][65];
  const int k0 = blockIdx.y * 64, n0 = blockIdx.x * 64;
  const int tx = threadIdx.x, ty = threadIdx.y;
#pragma unroll
  for (int r = ty; r < 64; r += 4)
    tile[r][tx] = in[(long)(k0 + r) * N + n0 + tx];
  __syncthreads();
#pragma unroll
  for (int r = ty; r < 64; r += 4)
    out[(long)(n0 + r) * K + k0 + tx] = f2bf(tile[tx][r]);
}

// -- batched (z): fp32 [K][N] -> bf16 [N][K] scaled by g[k]; NO atomics ------
// per-block (u,v) partials -> pup[kblk][z*N + n]; reduced by uv_reduce_k.
// (r14-verified: removed the 786K contended atomicAdds of the r11 version)
__global__ __launch_bounds__(256) void transpose_scale_k(
    const float* __restrict__ in0, const float* __restrict__ g0,
    const float* __restrict__ beta0, ushort* __restrict__ out0,
    float2* __restrict__ pup, int K, int N)
{
  __shared__ float tile[64][65];
  __shared__ float2 pred[4][64];
  const int z = blockIdx.z;
  const float* in    = in0 + (long)z * K * N;
  const float* g     = g0 + (long)z * K;
  const float* beta  = beta0 + (long)z * K;
  ushort* out        = out0 + (long)z * K * N;
  const int k0 = blockIdx.y * 64, n0 = blockIdx.x * 64;
  const int tx = threadIdx.x, ty = threadIdx.y;
  float pu = 0.f, pv = 0.f;
#pragma unroll
  for (int r = ty; r < 64; r += 4) {
    const float w  = in[(long)(k0 + r) * N + n0 + tx];
    const float ws = g[k0 + r] * w;
    tile[r][tx] = ws;
    pu += ws;
    pv += beta[k0 + r] * w;
  }
  pred[ty][tx] = make_float2(pu, pv);
  __syncthreads();
  if (ty == 0) {
    const float2 a = pred[0][tx], b = pred[1][tx], c = pred[2][tx], d = pred[3][tx];
    const long ZN = (long)gridDim.z * N;
    pup[(long)blockIdx.y * ZN + (long)z * N + n0 + tx] =
        make_float2(a.x + b.x + c.x + d.x, a.y + b.y + c.y + d.y);
  }
#pragma unroll
  for (int r = ty; r < 64; r += 4)
    out[(long)(n0 + r) * K + k0 + tx] = f2bf(tile[tx][r]);
}

// ---------------- reduce pup[NK][ZN] -> uvw[ZN] ------------------------------
__global__ __launch_bounds__(256) void uv_reduce_k(
    const float2* __restrict__ pup, float2* __restrict__ uvw, int NK, int ZN)
{
  const int c = blockIdx.x * 256 + threadIdx.x;
  float sx = 0.f, sy = 0.f;
  for (int k = 0; k < NK; ++k) {
    const float2 v = pup[(long)k * ZN + c];
    sx += v.x; sy += v.y;
  }
  uvw[c] = make_float2(sx, sy);
}

// ---------------- combine: out[i] += part[i] (f32, vectorized) --------------
__global__ __launch_bounds__(512) void combine_k(
    float* __restrict__ out, const float* __restrict__ part)
{
  const long i = ((long)blockIdx.x * 512 + threadIdx.x) * 4;
  float4 a = *reinterpret_cast<const float4*>(out + i);
  float4 b = *reinterpret_cast<const float4*>(part + i);
  a.x += b.x; a.y += b.y; a.z += b.z; a.w += b.w;
  *reinterpret_cast<float4*>(out + i) = a;
}

// ============================================================================
// 256x256 GEMM — r9/r11 pipelined core, 16x16x32 MFMA (verified best:
// 72.6us / 947 TF / 0 bank conflicts). Modes:
//   MODE 0: C = silu(acc+bias) -> bf16                       (stem)
//   MODE 3: C = Rin + silu(rstd*acc - mu*rstd*u + v + b) -> bf16 (block)
//   MODE 5: split-K=2 head: kb=bid>>7; kb0 -> Cv (with consts), kb1 -> Cv2.
// ============================================================================
#define STG(gsrc, ldst)                                                          \
  __builtin_amdgcn_global_load_lds(AS1(gsrc),          AS3(ldst),          16, 0, 0); \
  __builtin_amdgcn_global_load_lds(AS1((gsrc) + offQ), AS3((ldst) + 8192), 16, 0, 0)

#define ldsA(B, H) (ldsW + (B) * 65536 + (H) * 16384)
#define ldsB(B, H) (ldsW + (B) * 65536 + 32768 + (H) * 16384)

#define RD_AF(DST, DB, MH, KS)                                                  \
  _Pragma("unroll") for (int i_ = 0; i_ < 4; ++i_)                              \
    DST[i_] = *(const short8*)(smem + (DB) * 65536 + aOff + ((MH) * 4 + i_) * 2048 + rdk[(KS)])

#define RD_BF(DST, DB, KS)                                                      \
  _Pragma("unroll") for (int j_ = 0; j_ < 4; ++j_)                              \
    DST[j_] = *(const short8*)(smem + (DB) * 65536 + bOff + j_ * 2048 + rdk[(KS)])

#define MFMA16(AREG, MH, BREG)                                                  \
  _Pragma("unroll") for (int i_ = 0; i_ < 4; ++i_)                              \
  _Pragma("unroll") for (int j_ = 0; j_ < 4; ++j_)                              \
    acc[(MH) * 4 + i_][j_] = __builtin_amdgcn_mfma_f32_16x16x32_bf16(           \
        AREG[i_], BREG[j_], acc[(MH) * 4 + i_][j_], 0, 0, 0)

#define BARRIER __builtin_amdgcn_s_barrier()
#define SP1 __builtin_amdgcn_s_setprio(1)
#define SP0 __builtin_amdgcn_s_setprio(0)
#define SBAR __builtin_amdgcn_sched_barrier(0)
#define LGKMW(N) do { asm volatile("s_waitcnt lgkmcnt(" #N ")"); SBAR; } while (0)
#define W4 do { asm volatile("s_waitcnt vmcnt(4)" ::: "memory"); SBAR; } while (0)
#define W0 do { asm volatile("s_waitcnt vmcnt(0)" ::: "memory"); SBAR; } while (0)
#define WN do {} while (0)

#define DO_TILE(DB, S1, AO, S2, BO, WAITE)                                      \
  RD_AF(afx, DB, 0, 0);                                                         \
  RD_BF(bf, DB, 0);                                                             \
  RD_AF(afy, DB, 1, 0);                                                         \
  if (S1) { STG(aP + (AO), ldsA((DB) ^ 1, 0));                                  \
            STG(aP + (AO) + offH, ldsA((DB) ^ 1, 1)); }                         \
  LGKMW(4);                                                                     \
  SP1; MFMA16(afx, 0, bf); SP0;                                                 \
  RD_AF(afx, DB, 0, 1);                                                         \
  LGKMW(4);                                                                     \
  SP1; MFMA16(afy, 1, bf); SP0;                                                 \
  RD_BF(bf, DB, 1);                                                             \
  SBAR;                                                                         \
  RD_AF(afy, DB, 1, 1);                                                         \
  LGKMW(4);                                                                     \
  SP1; MFMA16(afx, 0, bf); SP0;                                                 \
  BARRIER;                                                                      \
  if (S2) { STG(bP + (BO), ldsB(DB, 0));                                        \
            STG(bP + (BO) + offH, ldsB(DB, 1)); }                               \
  LGKMW(0);                                                                     \
  SP1; MFMA16(afy, 1, bf); SP0;                                                 \
  WAITE;                                                                        \
  BARRIER;

template<int MODE>
__global__ __launch_bounds__(512, 2) void gemm256_k(
    const ushort* __restrict__ A, const ushort* __restrict__ Bt,
    const float* __restrict__ bias, const float2* __restrict__ stats,
    const float2* __restrict__ uvw, const ushort* __restrict__ Rin,
    void* __restrict__ Cv, float* __restrict__ Cv2,
    int M, int N, int K, int ld)
{
  extern __shared__ char smem[];
  const int tid = threadIdx.x;
  const int lane = tid & 63, wid = tid >> 6;
  const int wr = wid >> 2, wc = wid & 3;
  const int nbx = N >> 8;

  int bid;
  {
    const int b = blockIdx.x;
    const int cpx = gridDim.x >> 3;
    bid = (b & 7) * cpx + (b >> 3);
  }
  int kb = 0;
  if (MODE == 5) { kb = bid >> 7; bid &= 127; }
  const int bx = bid % nbx, by = bid / nbx;
  const long m0 = (long)by << 8, n0 = (long)bx << 8;

  const int srow = tid >> 3;
  const int scol = (((tid & 7) * 16) ^ (((tid >> 3) & 7) << 4)) >> 1;
  const ushort* aP = A  + (long)kb * 1024 + (m0 + srow) * (long)ld + scol;
  const ushort* bP = Bt + (long)kb * 1024 + (n0 + srow) * (long)ld + scol;
  const long offH = 128L * ld, offQ = 64L * ld;
  char* ldsW = smem + wid * 1024;

  int rdk[2];
  rdk[0] = (((lane >> 4) * 16)     ) ^ ((lane & 7) << 4);
  rdk[1] = (((lane >> 4) * 16) + 64) ^ ((lane & 7) << 4);
  const int aOff = wr * 16384 + (lane & 15) * 128;
  const int bOff = 32768 + (wc >> 1) * 16384 + ((wc & 1) * 64 + (lane & 15)) * 128;

  f32x4 acc[8][4] = {};
  const int NT = K >> 6;  // even, >= 4

  // prologue: A(0), B(0), B(1); keep B(1) in flight
  STG(aP,      ldsA(0, 0));  STG(aP + offH,      ldsA(0, 1));
  STG(bP,      ldsB(0, 0));  STG(bP + offH,      ldsB(0, 1));
  STG(bP + 64, ldsB(1, 0));  STG(bP + 64 + offH, ldsB(1, 1));
  W4;
  BARRIER;

  short8 afx[4], afy[4], bf[4];
  for (int t = 0; t < NT - 2; t += 2) {
    DO_TILE(0, 1,  64, 1, 128, W4)
    DO_TILE(1, 1, 128, 1, 192, W4)
    aP += 128; bP += 128;
  }
  DO_TILE(0, 1, 64, 0, 0, W0)
  DO_TILE(1, 0,  0, 0, 0, WN)

  // ---- epilogue: C/D layout col=lane&15, row=(lane>>4)*4+reg ----
  if (MODE == 0) {
#pragma unroll
    for (int j = 0; j < 4; ++j) {
      const long col = n0 + wc * 64 + j * 16 + (lane & 15);
      const float bj = bias[col];
#pragma unroll
      for (int i = 0; i < 8; ++i) {
        const long rowb = m0 + wr * 128 + i * 16 + ((lane >> 4) << 2);
#pragma unroll
        for (int r = 0; r < 4; ++r) {
          const float v = acc[i][j][r] + bj;
          ((ushort*)Cv)[(rowb + r) * N + col] = f2bf(silu_f(v));
        }
      }
    }
  } else {
    float2 uvv[4];
    float  bj4[4];
    long   col4[4];
#pragma unroll
    for (int j = 0; j < 4; ++j) {
      col4[j] = n0 + wc * 64 + j * 16 + (lane & 15);
      uvv[j]  = uvw[col4[j]];
      bj4[j]  = bias[col4[j]];
    }
    float* dst = (MODE == 5 && kb == 1) ? Cv2 : (float*)Cv;
    const float cw = (MODE == 5 && kb == 1) ? 0.f : 1.f;
#pragma unroll
    for (int i = 0; i < 8; ++i) {
      const long rowb = m0 + wr * 128 + i * 16 + ((lane >> 4) << 2);
#pragma unroll
      for (int r = 0; r < 4; ++r) {
        const long row = rowb + r;
        const float2 ms = stats[row];  // {mu*rstd, rstd}
#pragma unroll
        for (int j = 0; j < 4; ++j) {
          const long idx = row * (long)N + col4[j];
          if (MODE == 3) {
            const float v = ms.y * acc[i][j][r] - ms.x * uvv[j].x + uvv[j].y + bj4[j];
            ((ushort*)Cv)[idx] = f2bf(bfu2f(Rin[idx]) + silu_f(v));
          } else {
            const float v = ms.y * acc[i][j][r]
                          + cw * (uvv[j].y + bj4[j] - ms.x * uvv[j].x);
            dst[idx] = v;
          }
        }
      }
    }
  }
}

// ---------------------------------------------------------------------------
extern "C" void kernel_launch(void* const* d_in, const int* in_sizes, int n_in,
                              void* d_out, int out_size, void* d_ws, size_t ws_size,
                              hipStream_t stream) {
  const float* x     = (const float*)d_in[0];
  const float* ln1_s = (const float*)d_in[1];
  const float* ln1_b = (const float*)d_in[2];
  const float* w1    = (const float*)d_in[3];
  const float* b1    = (const float*)d_in[4];
  const float* bln_s = (const float*)d_in[5];
  const float* bln_b = (const float*)d_in[6];
  const float* bws   = (const float*)d_in[7];
  const float* bbs   = (const float*)d_in[8];
  const float* ln2_s = (const float*)d_in[9];
  const float* ln2_b = (const float*)d_in[10];
  const float* w2    = (const float*)d_in[11];
  const float* b2    = (const float*)d_in[12];
  float* out = (float*)d_out;

  const int M = 8192;
  char* ws = (char*)d_ws;
  ushort* h0    = (ushort*)ws;                          // 8192x2048 bf16 = 32MB
  ushort* h1    = (ushort*)(ws + 33554432);             // 32MB (stem Abf / head partial)
  ushort* Abf   = h1;
  ushort* wt    = (ushort*)(ws + 67108864);             // bf16 weights^T, 56MB
  float2* uvw   = (float2*)(ws + 125829120);            // 7 x 2048 float2 = 112KB
  float2* stats = (float2*)(ws + 125829120 + 131072);   // 8192 float2 = 64KB
  float2* pupA  = (float2*)(ws + 125829120 + 131072 + 65536);          // 32x12288 f2
  float2* pupB  = (float2*)(ws + 125829120 + 131072 + 65536 + 3145728); // 32x1024 f2
  const long W1T = 0;
  const long BLK = 2097152;
  const long W2T = BLK + 6L * 4194304;

  (void)hipFuncSetAttribute((const void*)gemm256_k<0>,
      hipFuncAttributeMaxDynamicSharedMemorySize, 131072);
  (void)hipFuncSetAttribute((const void*)gemm256_k<3>,
      hipFuncAttributeMaxDynamicSharedMemorySize, 131072);
  (void)hipFuncSetAttribute((const void*)gemm256_k<5>,
      hipFuncAttributeMaxDynamicSharedMemorySize, 131072);

  dim3 tb(64, 4);
  transpose_bf16_k<<<dim3(32, 16), tb, 0, stream>>>(w1, wt + W1T, 1024, 2048);
  transpose_scale_k<<<dim3(32, 32, 6), tb, 0, stream>>>(
      bws, bln_s, bln_b, wt + BLK, pupA, 2048, 2048);
  uv_reduce_k<<<48, 256, 0, stream>>>(pupA, uvw, 32, 12288);
  transpose_scale_k<<<dim3(16, 32, 1), tb, 0, stream>>>(
      w2, ln2_s, ln2_b, wt + W2T, pupB, 2048, 1024);
  uv_reduce_k<<<4, 256, 0, stream>>>(pupB, uvw + 6L * 2048, 32, 1024);

  // stem: h0 = silu(LN(x) @ w1 + b1)
  ln_bf16_k<1><<<M, 256, 0, stream>>>(x, ln1_s, ln1_b, Abf);
  gemm256_k<0><<<32 * 8, 512, 131072, stream>>>(
      Abf, wt + W1T, b1, nullptr, nullptr, nullptr,
      (void*)h0, nullptr, M, 2048, 1024, 1024);

  // residual blocks (folded LN): h_out = h_in + silu(affine(h_in @ W'))
  ushort* hin = h0;
  ushort* hout = h1;
  for (int i = 0; i < 6; ++i) {
    ln_stats_k<<<M, 256, 0, stream>>>(hin, stats);
    gemm256_k<3><<<32 * 8, 512, 131072, stream>>>(
        hin, wt + BLK + (long)i * 4194304, bbs + i * 2048, stats,
        uvw + (long)i * 2048, hin, (void*)hout, nullptr, M, 2048, 2048, 2048);
    ushort* tmp = hin; hin = hout; hout = tmp;
  }

  // head (folded LN, split-K=2, deterministic): hin == h0, h1 free -> partial
  float* part = (float*)h1;
  ln_stats_k<<<M, 256, 0, stream>>>(hin, stats);
  gemm256_k<5><<<32 * 4 * 2, 512, 131072, stream>>>(
      hin, wt + W2T, b2, stats, uvw + 6L * 2048, nullptr,
      (void*)out, part, M, 1024, 1024, 2048);
  combine_k<<<4096, 512, 0, stream>>>(out, part);
}